// Round 1
// baseline (559.623 us; speedup 1.0000x reference)
//
#include <hip/hip_runtime.h>
#include <hip/hip_bf16.h>
#include <stdint.h>

// Problem constants
#define S_LEN 2048
#define BATCH 32
#define DDIM  1024
#define E2DIM 1024
#define MROWS (S_LEN*BATCH)   // 65536 GEMM rows

typedef __attribute__((ext_vector_type(8))) short bf16x8;
typedef __attribute__((ext_vector_type(4))) float f32x4;

__device__ inline unsigned int pk2bf(float a, float b) {
  float2 t; t.x = a; t.y = b;
  __hip_bfloat162 h = __float22bfloat162_rn(t);
  union { __hip_bfloat162 h; unsigned int u; } c; c.h = h;
  return c.u;
}

__device__ inline void gload_lds16(const void* g, void* l) {
  __builtin_amdgcn_global_load_lds(
      (const __attribute__((address_space(1))) unsigned int*)g,
      (__attribute__((address_space(3))) unsigned int*)l, 16, 0, 0);
}

__device__ inline float fast_tanh(float x) {
  // tanh(x) = 1 - 2/(exp(2x)+1); inf-safe at both ends
  float e = __expf(2.0f * x);
  return 1.0f - 2.0f / (e + 1.0f);
}

// ---------------------------------------------------------------------------
// prep: blocks 0..63 convert Wc (fp32 [D][E2]) -> bf16; blocks 64..95 compute
// weighted_s[b][n] = sum_d dec[b][d]*Wb[n][d]  (tiny fp32 GEMM, LDS-tiled)
// ---------------------------------------------------------------------------
__global__ __launch_bounds__(256) void prep_kernel(
    const float* __restrict__ dec, const float* __restrict__ Wb,
    const float* __restrict__ Wc, unsigned short* __restrict__ WcBf,
    float* __restrict__ wsum)
{
  const int t = threadIdx.x;
  if (blockIdx.x < 64) {
    const int base = blockIdx.x * 16384;
    for (int i = 0; i < 16; ++i) {
      int idx = base + i * 1024 + t * 4;
      float4 v = *(const float4*)(Wc + idx);
      uint2 w; w.x = pk2bf(v.x, v.y); w.y = pk2bf(v.z, v.w);
      *(uint2*)(WcBf + idx) = w;
    }
  } else {
    const int j = blockIdx.x - 64;          // n-slice [j*32, j*32+32)
    __shared__ float sdec[32][65];          // +1 pad: bank-conflict-free
    __shared__ float swb[32][65];
    const int b = t & 31, nl = t >> 5;      // thread owns (b, {nl,nl+8,nl+16,nl+24})
    float acc0 = 0.f, acc1 = 0.f, acc2 = 0.f, acc3 = 0.f;
    for (int c = 0; c < 16; ++c) {          // d-chunks of 64
      __syncthreads();
      for (int idx = t; idx < 2048; idx += 256) {
        int rr = idx >> 6, dd = idx & 63;
        sdec[rr][dd] = dec[rr * 1024 + c * 64 + dd];
        swb[rr][dd]  = Wb[(size_t)(j * 32 + rr) * 1024 + c * 64 + dd];
      }
      __syncthreads();
      #pragma unroll 8
      for (int dd = 0; dd < 64; ++dd) {
        float dv = sdec[b][dd];
        acc0 += dv * swb[nl][dd];
        acc1 += dv * swb[nl + 8][dd];
        acc2 += dv * swb[nl + 16][dd];
        acc3 += dv * swb[nl + 24][dd];
      }
    }
    wsum[b * 1024 + j * 32 + nl]      = acc0;
    wsum[b * 1024 + j * 32 + nl + 8]  = acc1;
    wsum[b * 1024 + j * 32 + nl + 16] = acc2;
    wsum[b * 1024 + j * 32 + nl + 24] = acc3;
  }
}

// ---------------------------------------------------------------------------
// score: per 128-row M-panel, loop all 8 N-blocks (enc read from HBM once).
// C-tile 128x128, 4 waves in 2x2 (each wave 64x64 = 4x4 16x16x32 frags).
// A: fp32 global -> regs -> bf16 -> LDS.  B: bf16 ws -> global_load_lds(16B).
// Epilogue: score[r] += sum_col tanh(acc + wsum[b][col]) * Wa[col].
// ---------------------------------------------------------------------------
__global__ __launch_bounds__(256, 2) void score_kernel(
    const float* __restrict__ enc, const unsigned short* __restrict__ WcBf,
    const float* __restrict__ wsum, const float* __restrict__ Wa,
    float* __restrict__ score)
{
  __shared__ unsigned short Albs[128][32];  // 8 KB bf16 A tile
  __shared__ unsigned short Blbs[128][32];  // 8 KB bf16 B tile
  __shared__ float WaLds[1024];             // 4 KB
  __shared__ float scorep[128];

  const int tid = threadIdx.x;
  const int wid = tid >> 6, lane = tid & 63;
  const int l15 = lane & 15, q = lane >> 4;
  const int wr = wid >> 1, wc = wid & 1;
  const long rowBase = (long)blockIdx.x * 128;

  for (int i = tid; i < 1024; i += 256) WaLds[i] = Wa[i];
  if (tid < 128) scorep[tid] = 0.0f;

  // staging assignment
  const int arow = tid >> 1, ak = (tid & 1) * 16;   // A: 16 fp32 per thread
  const float* aptr = enc + ((size_t)(rowBase + arow)) * 1024 + ak;
  const int brow = tid >> 2, bk = (tid & 3) * 8;    // B: 16 B per thread x2

  for (int nb = 0; nb < 8; ++nb) {
    f32x4 acc[4][4];
    #pragma unroll
    for (int m = 0; m < 4; ++m)
      #pragma unroll
      for (int n = 0; n < 4; ++n) {
        f32x4 z = {0.f, 0.f, 0.f, 0.f};
        acc[m][n] = z;
      }

    const unsigned short* bsrc = WcBf + ((size_t)(nb * 128 + brow)) * 1024 + bk;

    for (int kt = 0; kt < 32; ++kt) {
      // issue B async stage first (in flight during A convert)
      gload_lds16(bsrc + kt * 32, &Blbs[brow][bk]);
      gload_lds16(bsrc + kt * 32 + 64 * 1024, &Blbs[64 + brow][bk]);
      // A stage: 16 fp32 -> 16 bf16 -> 32B LDS write
      const float4* ap = (const float4*)(aptr + kt * 32);
      float4 v0 = ap[0], v1 = ap[1], v2 = ap[2], v3 = ap[3];
      uint4 w;
      w.x = pk2bf(v0.x, v0.y); w.y = pk2bf(v0.z, v0.w);
      w.z = pk2bf(v1.x, v1.y); w.w = pk2bf(v1.z, v1.w);
      *(uint4*)&Albs[arow][ak] = w;
      w.x = pk2bf(v2.x, v2.y); w.y = pk2bf(v2.z, v2.w);
      w.z = pk2bf(v3.x, v3.y); w.w = pk2bf(v3.z, v3.w);
      *(uint4*)&Albs[arow][ak + 8] = w;
      __syncthreads();

      bf16x8 af[4], bfr[4];
      #pragma unroll
      for (int m = 0; m < 4; ++m)
        af[m] = *(const bf16x8*)&Albs[wr * 64 + m * 16 + l15][q * 8];
      #pragma unroll
      for (int n = 0; n < 4; ++n)
        bfr[n] = *(const bf16x8*)&Blbs[wc * 64 + n * 16 + l15][q * 8];
      #pragma unroll
      for (int m = 0; m < 4; ++m)
        #pragma unroll
        for (int n = 0; n < 4; ++n)
          acc[m][n] = __builtin_amdgcn_mfma_f32_16x16x32_bf16(
              af[m], bfr[n], acc[m][n], 0, 0, 0);
      __syncthreads();
    }

    // epilogue for this n-block
    #pragma unroll
    for (int m = 0; m < 4; ++m) {
      #pragma unroll
      for (int r = 0; r < 4; ++r) {
        const int rowl = wr * 64 + m * 16 + q * 4 + r;
        const int bb = rowl & 31;                 // global row % 32 == rowl % 32
        float v = 0.f;
        #pragma unroll
        for (int n = 0; n < 4; ++n) {
          const int col = nb * 128 + wc * 64 + n * 16 + l15;
          float x = acc[m][n][r] + wsum[bb * 1024 + col];
          v += fast_tanh(x) * WaLds[col];
        }
        v += __shfl_xor(v, 1); v += __shfl_xor(v, 2);
        v += __shfl_xor(v, 4); v += __shfl_xor(v, 8);
        if (l15 == 0) atomicAdd(&scorep[rowl], v);
      }
    }
  }
  __syncthreads();
  if (tid < 128) score[rowBase + tid] = scorep[tid];
}

// ---------------------------------------------------------------------------
// softmax over s (axis 0) per batch column b
// ---------------------------------------------------------------------------
__global__ __launch_bounds__(256) void softmax_kernel(
    const float* __restrict__ score, float* __restrict__ attn)
{
  const int b = blockIdx.x, t = threadIdx.x;
  __shared__ float red[256];
  float m = -1e30f;
  for (int s = t; s < S_LEN; s += 256) m = fmaxf(m, score[s * 32 + b]);
  red[t] = m; __syncthreads();
  for (int o = 128; o > 0; o >>= 1) {
    if (t < o) red[t] = fmaxf(red[t], red[t + o]);
    __syncthreads();
  }
  const float mx = red[0]; __syncthreads();
  float sum = 0.f;
  for (int s = t; s < S_LEN; s += 256) sum += __expf(score[s * 32 + b] - mx);
  red[t] = sum; __syncthreads();
  for (int o = 128; o > 0; o >>= 1) {
    if (t < o) red[t] += red[t + o];
    __syncthreads();
  }
  const float inv = 1.0f / red[0];
  for (int s = t; s < S_LEN; s += 256)
    attn[s * 32 + b] = __expf(score[s * 32 + b] - mx) * inv;
}

// ---------------------------------------------------------------------------
// context[b][e] = sum_s attn[s][b] * enc[s][b][e] — streaming, partials + reduce
// ---------------------------------------------------------------------------
__global__ __launch_bounds__(256) void ctx_partial_kernel(
    const float* __restrict__ enc, const float* __restrict__ attn,
    float* __restrict__ partial)
{
  const int blk = blockIdx.x;
  const int b = blk & 31, sc = blk >> 5;    // 16 s-chunks of 128
  const int t = threadIdx.x;
  float4 acc = make_float4(0.f, 0.f, 0.f, 0.f);
  const size_t ebase = (size_t)t * 4;
  #pragma unroll 4
  for (int si = 0; si < 128; ++si) {
    const int s = sc * 128 + si;
    const float a = attn[s * 32 + b];
    const float4 v = *(const float4*)(enc + ((size_t)s * 32 + b) * 1024 + ebase);
    acc.x += a * v.x; acc.y += a * v.y; acc.z += a * v.z; acc.w += a * v.w;
  }
  *(float4*)(partial + ((size_t)(sc * 32 + b)) * 1024 + ebase) = acc;
}

__global__ __launch_bounds__(256) void ctx_reduce_kernel(
    const float* __restrict__ partial, float* __restrict__ out)
{
  const int b = blockIdx.x, t = threadIdx.x;
  float4 acc = make_float4(0.f, 0.f, 0.f, 0.f);
  #pragma unroll
  for (int p = 0; p < 16; ++p) {
    float4 v = *(const float4*)(partial + ((size_t)(p * 32 + b)) * 1024 + t * 4);
    acc.x += v.x; acc.y += v.y; acc.z += v.z; acc.w += v.w;
  }
  *(float4*)(out + (size_t)b * 1024 + t * 4) = acc;
}

// ---------------------------------------------------------------------------
extern "C" void kernel_launch(void* const* d_in, const int* in_sizes, int n_in,
                              void* d_out, int out_size, void* d_ws, size_t ws_size,
                              hipStream_t stream) {
  const float* dec = (const float*)d_in[0];
  const float* enc = (const float*)d_in[1];
  const float* Wb  = (const float*)d_in[2];
  const float* Wc  = (const float*)d_in[3];
  const float* Wa  = (const float*)d_in[4];
  float* out = (float*)d_out;

  char* ws = (char*)d_ws;
  unsigned short* WcBf = (unsigned short*)ws;                    // 2 MB
  float* wsum    = (float*)(ws + (2u << 20));                    // 128 KB
  float* score   = (float*)(ws + (2u << 20) + (128u << 10));     // 256 KB
  float* attn    = (float*)(ws + (2u << 20) + (384u << 10));     // 256 KB
  float* partial = (float*)(ws + (2u << 20) + (640u << 10));     // 2 MB
  (void)ws_size; (void)in_sizes; (void)n_in; (void)out_size;

  prep_kernel<<<96, 256, 0, stream>>>(dec, Wb, Wc, WcBf, wsum);
  score_kernel<<<512, 256, 0, stream>>>(enc, WcBf, wsum, Wa, score);
  softmax_kernel<<<32, 256, 0, stream>>>(score, attn);
  ctx_partial_kernel<<<512, 256, 0, stream>>>(enc, attn, partial);
  ctx_reduce_kernel<<<32, 256, 0, stream>>>(partial, out);
}

// Round 2
// 441.208 us; speedup vs baseline: 1.2684x; 1.2684x over previous
//
#include <hip/hip_runtime.h>
#include <hip/hip_bf16.h>
#include <stdint.h>

// Problem constants
#define S_LEN 2048
#define BATCH 32
#define DDIM  1024
#define E2DIM 1024
#define MROWS (S_LEN*BATCH)   // 65536 GEMM rows

typedef __attribute__((ext_vector_type(8))) short bf16x8;
typedef __attribute__((ext_vector_type(4))) float f32x4;

__device__ inline unsigned int pk2bf(float a, float b) {
  float2 t; t.x = a; t.y = b;
  __hip_bfloat162 h = __float22bfloat162_rn(t);
  union { __hip_bfloat162 h; unsigned int u; } c; c.h = h;
  return c.u;
}

__device__ inline float bflo(unsigned int u) { return __uint_as_float(u << 16); }
__device__ inline float bfhi(unsigned int u) { return __uint_as_float(u & 0xffff0000u); }

__device__ inline void gload_lds16(const void* g, void* l) {
  __builtin_amdgcn_global_load_lds(
      (const __attribute__((address_space(1))) unsigned int*)g,
      (__attribute__((address_space(3))) unsigned int*)l, 16, 0, 0);
}

__device__ inline float fast_tanh(float x) {
  float e = __expf(2.0f * x);
  return 1.0f - 2.0f / (e + 1.0f);
}

// ---------------------------------------------------------------------------
// conv: enc fp32 [S*B*E2] -> bf16 (streaming, 16B stores)
// ---------------------------------------------------------------------------
__global__ __launch_bounds__(256) void conv_kernel(
    const float* __restrict__ enc, unsigned short* __restrict__ encBf)
{
  const size_t n8 = (size_t)MROWS * 1024 / 8;   // 8M chunks of 8 elems
  const size_t stride = (size_t)gridDim.x * 256;
  for (size_t i = (size_t)blockIdx.x * 256 + threadIdx.x; i < n8; i += stride) {
    const float4* p = (const float4*)enc + i * 2;
    float4 a = p[0], b = p[1];
    uint4 w;
    w.x = pk2bf(a.x, a.y); w.y = pk2bf(a.z, a.w);
    w.z = pk2bf(b.x, b.y); w.w = pk2bf(b.z, b.w);
    ((uint4*)encBf)[i] = w;
  }
}

// ---------------------------------------------------------------------------
// prep: blocks 0..63 convert Wc -> bf16; blocks 64..95 wsum = dec @ Wb^T
// ---------------------------------------------------------------------------
__global__ __launch_bounds__(256) void prep_kernel(
    const float* __restrict__ dec, const float* __restrict__ Wb,
    const float* __restrict__ Wc, unsigned short* __restrict__ WcBf,
    float* __restrict__ wsum)
{
  const int t = threadIdx.x;
  if (blockIdx.x < 64) {
    const int base = blockIdx.x * 16384;
    for (int i = 0; i < 16; ++i) {
      int idx = base + i * 1024 + t * 4;
      float4 v = *(const float4*)(Wc + idx);
      uint2 w; w.x = pk2bf(v.x, v.y); w.y = pk2bf(v.z, v.w);
      *(uint2*)(WcBf + idx) = w;
    }
  } else {
    const int j = blockIdx.x - 64;
    __shared__ float sdec[32][65];
    __shared__ float swb[32][65];
    const int b = t & 31, nl = t >> 5;
    float acc0 = 0.f, acc1 = 0.f, acc2 = 0.f, acc3 = 0.f;
    for (int c = 0; c < 16; ++c) {
      __syncthreads();
      for (int idx = t; idx < 2048; idx += 256) {
        int rr = idx >> 6, dd = idx & 63;
        sdec[rr][dd] = dec[rr * 1024 + c * 64 + dd];
        swb[rr][dd]  = Wb[(size_t)(j * 32 + rr) * 1024 + c * 64 + dd];
      }
      __syncthreads();
      #pragma unroll 8
      for (int dd = 0; dd < 64; ++dd) {
        float dv = sdec[b][dd];
        acc0 += dv * swb[nl][dd];
        acc1 += dv * swb[nl + 8][dd];
        acc2 += dv * swb[nl + 16][dd];
        acc3 += dv * swb[nl + 24][dd];
      }
    }
    wsum[b * 1024 + j * 32 + nl]      = acc0;
    wsum[b * 1024 + j * 32 + nl + 8]  = acc1;
    wsum[b * 1024 + j * 32 + nl + 16] = acc2;
    wsum[b * 1024 + j * 32 + nl + 24] = acc3;
  }
}

// ---------------------------------------------------------------------------
// score (bf16 path): 64-row M-panels (grid 1024 -> 4 blocks/CU), BK=64,
// tile 64x128 per n-panel, 4 waves 2x2 (wave = 32x64 = 2x4 frags).
// Both operands staged via global_load_lds(16B) with XOR chunk-swizzle:
// LDS slot (r,c) holds global chunk (r, c^(r&7)); reads apply same XOR.
// Epilogue folds tanh(.+wsum) . Wa into 64 score rows (never materializes H).
// ---------------------------------------------------------------------------
__global__ __launch_bounds__(256, 4) void score_kernel(
    const unsigned short* __restrict__ encBf, const unsigned short* __restrict__ WcBf,
    const float* __restrict__ wsum, const float* __restrict__ Wa,
    float* __restrict__ score)
{
  __shared__ unsigned short Albs[64][64];    // 8 KB  (64 rows x BK=64 bf16)
  __shared__ unsigned short Blbs[128][64];   // 16 KB (128 cols x BK=64 bf16)
  __shared__ float WaLds[1024];
  __shared__ float scorep[64];

  const int tid = threadIdx.x;
  const int lane = tid & 63;
  const int l15 = lane & 15, q = lane >> 4;
  const int wid = tid >> 6;
  const int wr = wid >> 1, wc = wid & 1;
  const size_t rowBase = (size_t)blockIdx.x * 64;

  for (int i = tid; i < 1024; i += 256) WaLds[i] = Wa[i];
  if (tid < 64) scorep[tid] = 0.f;

  // A staging: 512 slots of 16B, 2 per thread. slot s: r=s>>3, c=s&7.
  const int as0 = tid, as1 = 256 + tid;
  const int ar0 = as0 >> 3, ac0 = as0 & 7;
  const int ar1 = as1 >> 3, ac1 = as1 & 7;
  const unsigned short* aSrc0 = encBf + (rowBase + ar0) * 1024 + ((ac0 ^ (ar0 & 7)) * 8);
  const unsigned short* aSrc1 = encBf + (rowBase + ar1) * 1024 + ((ac1 ^ (ar1 & 7)) * 8);
  unsigned short* aDst0 = &Albs[0][0] + (size_t)as0 * 8;
  unsigned short* aDst1 = &Albs[0][0] + (size_t)as1 * 8;

  // B staging: 1024 slots, 4 per thread.
  int bOff[4]; unsigned short* bDst[4];
  #pragma unroll
  for (int k = 0; k < 4; ++k) {
    const int s = k * 256 + tid;
    const int r = s >> 3, c = s & 7;
    bOff[k] = r * 1024 + ((c ^ (r & 7)) * 8);
    bDst[k] = &Blbs[0][0] + (size_t)s * 8;
  }

  for (int nb = 0; nb < 8; ++nb) {
    f32x4 acc[2][4];
    #pragma unroll
    for (int m = 0; m < 2; ++m)
      #pragma unroll
      for (int n = 0; n < 4; ++n) { f32x4 z = {0.f,0.f,0.f,0.f}; acc[m][n] = z; }

    const unsigned short* bPanel = WcBf + (size_t)nb * 128 * 1024;

    for (int kt = 0; kt < 16; ++kt) {
      const int ko = kt * 64;
      gload_lds16(aSrc0 + ko, aDst0);
      gload_lds16(aSrc1 + ko, aDst1);
      #pragma unroll
      for (int k = 0; k < 4; ++k)
        gload_lds16(bPanel + ko + bOff[k], bDst[k]);
      __syncthreads();

      #pragma unroll
      for (int kk = 0; kk < 2; ++kk) {
        bf16x8 af[2], bfv[4];
        #pragma unroll
        for (int m = 0; m < 2; ++m) {
          const int row = wr * 32 + m * 16 + l15;
          const int ch = (kk * 4 + q) ^ (row & 7);
          af[m] = *(const bf16x8*)&Albs[row][ch * 8];
        }
        #pragma unroll
        for (int n = 0; n < 4; ++n) {
          const int row = wc * 64 + n * 16 + l15;
          const int ch = (kk * 4 + q) ^ (row & 7);
          bfv[n] = *(const bf16x8*)&Blbs[row][ch * 8];
        }
        #pragma unroll
        for (int m = 0; m < 2; ++m)
          #pragma unroll
          for (int n = 0; n < 4; ++n)
            acc[m][n] = __builtin_amdgcn_mfma_f32_16x16x32_bf16(
                af[m], bfv[n], acc[m][n], 0, 0, 0);
      }
      __syncthreads();
    }

    // epilogue for this n-panel
    #pragma unroll
    for (int m = 0; m < 2; ++m) {
      #pragma unroll
      for (int i = 0; i < 4; ++i) {
        const int rowl = wr * 32 + m * 16 + q * 4 + i;
        const int bb = rowl & 31;     // (rowBase+rowl)%32 == rowl%32
        float v = 0.f;
        #pragma unroll
        for (int n = 0; n < 4; ++n) {
          const int col = nb * 128 + wc * 64 + n * 16 + l15;
          float x = acc[m][n][i] + wsum[bb * 1024 + col];
          v += fast_tanh(x) * WaLds[col];
        }
        v += __shfl_xor(v, 1); v += __shfl_xor(v, 2);
        v += __shfl_xor(v, 4); v += __shfl_xor(v, 8);
        if (l15 == 0) atomicAdd(&scorep[rowl], v);
      }
    }
  }
  __syncthreads();
  if (tid < 64) score[rowBase + tid] = scorep[tid];
}

// ---------------------------------------------------------------------------
// softmax over s (axis 0) per batch column b
// ---------------------------------------------------------------------------
__global__ __launch_bounds__(256) void softmax_kernel(
    const float* __restrict__ score, float* __restrict__ attn)
{
  const int b = blockIdx.x, t = threadIdx.x;
  __shared__ float red[256];
  float m = -1e30f;
  for (int s = t; s < S_LEN; s += 256) m = fmaxf(m, score[s * 32 + b]);
  red[t] = m; __syncthreads();
  for (int o = 128; o > 0; o >>= 1) {
    if (t < o) red[t] = fmaxf(red[t], red[t + o]);
    __syncthreads();
  }
  const float mx = red[0]; __syncthreads();
  float sum = 0.f;
  for (int s = t; s < S_LEN; s += 256) sum += __expf(score[s * 32 + b] - mx);
  red[t] = sum; __syncthreads();
  for (int o = 128; o > 0; o >>= 1) {
    if (t < o) red[t] += red[t + o];
    __syncthreads();
  }
  const float inv = 1.0f / red[0];
  for (int s = t; s < S_LEN; s += 256)
    attn[s * 32 + b] = __expf(score[s * 32 + b] - mx) * inv;
}

// ---------------------------------------------------------------------------
// context: bf16-enc streaming partials + reduce
// ---------------------------------------------------------------------------
__global__ __launch_bounds__(256) void ctx_partial_bf16(
    const unsigned short* __restrict__ encBf, const float* __restrict__ attn,
    float* __restrict__ partial)
{
  const int blk = blockIdx.x;
  const int b = blk & 31, sc = blk >> 5;
  const int t = threadIdx.x;
  float a0 = 0.f, a1 = 0.f, a2 = 0.f, a3 = 0.f;
  const int e0 = t * 4;
  #pragma unroll 4
  for (int si = 0; si < 128; ++si) {
    const int s = sc * 128 + si;
    const float a = attn[s * 32 + b];
    uint2 w = *(const uint2*)(encBf + ((size_t)s * 32 + b) * 1024 + e0);
    a0 += a * bflo(w.x); a1 += a * bfhi(w.x);
    a2 += a * bflo(w.y); a3 += a * bfhi(w.y);
  }
  *(float4*)(partial + ((size_t)(sc * 32 + b)) * 1024 + e0) =
      make_float4(a0, a1, a2, a3);
}

__global__ __launch_bounds__(256) void ctx_reduce_kernel(
    const float* __restrict__ partial, float* __restrict__ out)
{
  const int b = blockIdx.x, t = threadIdx.x;
  float4 acc = make_float4(0.f, 0.f, 0.f, 0.f);
  #pragma unroll
  for (int p = 0; p < 16; ++p) {
    float4 v = *(const float4*)(partial + ((size_t)(p * 32 + b)) * 1024 + t * 4);
    acc.x += v.x; acc.y += v.y; acc.z += v.z; acc.w += v.w;
  }
  *(float4*)(out + (size_t)b * 1024 + t * 4) = acc;
}

// ---------------------------------------------------------------------------
// Fallback kernels (round-1 fp32-A path), used only if ws_size is too small
// ---------------------------------------------------------------------------
__global__ __launch_bounds__(256, 2) void score_f32_kernel(
    const float* __restrict__ enc, const unsigned short* __restrict__ WcBf,
    const float* __restrict__ wsum, const float* __restrict__ Wa,
    float* __restrict__ score)
{
  __shared__ unsigned short Albs[128][32];
  __shared__ unsigned short Blbs[128][32];
  __shared__ float WaLds[1024];
  __shared__ float scorep[128];

  const int tid = threadIdx.x;
  const int wid = tid >> 6, lane = tid & 63;
  const int l15 = lane & 15, q = lane >> 4;
  const int wr = wid >> 1, wc = wid & 1;
  const long rowBase = (long)blockIdx.x * 128;

  for (int i = tid; i < 1024; i += 256) WaLds[i] = Wa[i];
  if (tid < 128) scorep[tid] = 0.0f;

  const int arow = tid >> 1, ak = (tid & 1) * 16;
  const float* aptr = enc + ((size_t)(rowBase + arow)) * 1024 + ak;
  const int brow = tid >> 2, bk = (tid & 3) * 8;

  for (int nb = 0; nb < 8; ++nb) {
    f32x4 acc[4][4];
    #pragma unroll
    for (int m = 0; m < 4; ++m)
      #pragma unroll
      for (int n = 0; n < 4; ++n) { f32x4 z = {0.f,0.f,0.f,0.f}; acc[m][n] = z; }

    const unsigned short* bsrc = WcBf + ((size_t)(nb * 128 + brow)) * 1024 + bk;

    for (int kt = 0; kt < 32; ++kt) {
      gload_lds16(bsrc + kt * 32, &Blbs[brow][bk]);
      gload_lds16(bsrc + kt * 32 + 64 * 1024, &Blbs[64 + brow][bk]);
      const float4* ap = (const float4*)(aptr + kt * 32);
      float4 v0 = ap[0], v1 = ap[1], v2 = ap[2], v3 = ap[3];
      uint4 w;
      w.x = pk2bf(v0.x, v0.y); w.y = pk2bf(v0.z, v0.w);
      w.z = pk2bf(v1.x, v1.y); w.w = pk2bf(v1.z, v1.w);
      *(uint4*)&Albs[arow][ak] = w;
      w.x = pk2bf(v2.x, v2.y); w.y = pk2bf(v2.z, v2.w);
      w.z = pk2bf(v3.x, v3.y); w.w = pk2bf(v3.z, v3.w);
      *(uint4*)&Albs[arow][ak + 8] = w;
      __syncthreads();

      bf16x8 af[4], bfr[4];
      #pragma unroll
      for (int m = 0; m < 4; ++m)
        af[m] = *(const bf16x8*)&Albs[wr * 64 + m * 16 + l15][q * 8];
      #pragma unroll
      for (int n = 0; n < 4; ++n)
        bfr[n] = *(const bf16x8*)&Blbs[wc * 64 + n * 16 + l15][q * 8];
      #pragma unroll
      for (int m = 0; m < 4; ++m)
        #pragma unroll
        for (int n = 0; n < 4; ++n)
          acc[m][n] = __builtin_amdgcn_mfma_f32_16x16x32_bf16(
              af[m], bfr[n], acc[m][n], 0, 0, 0);
      __syncthreads();
    }

    #pragma unroll
    for (int m = 0; m < 4; ++m) {
      #pragma unroll
      for (int r = 0; r < 4; ++r) {
        const int rowl = wr * 64 + m * 16 + q * 4 + r;
        const int bb = rowl & 31;
        float v = 0.f;
        #pragma unroll
        for (int n = 0; n < 4; ++n) {
          const int col = nb * 128 + wc * 64 + n * 16 + l15;
          float x = acc[m][n][r] + wsum[bb * 1024 + col];
          v += fast_tanh(x) * WaLds[col];
        }
        v += __shfl_xor(v, 1); v += __shfl_xor(v, 2);
        v += __shfl_xor(v, 4); v += __shfl_xor(v, 8);
        if (l15 == 0) atomicAdd(&scorep[rowl], v);
      }
    }
  }
  __syncthreads();
  if (tid < 128) score[rowBase + tid] = scorep[tid];
}

__global__ __launch_bounds__(256) void ctx_partial_f32(
    const float* __restrict__ enc, const float* __restrict__ attn,
    float* __restrict__ partial)
{
  const int blk = blockIdx.x;
  const int b = blk & 31, sc = blk >> 5;
  const int t = threadIdx.x;
  float4 acc = make_float4(0.f, 0.f, 0.f, 0.f);
  const size_t ebase = (size_t)t * 4;
  #pragma unroll 4
  for (int si = 0; si < 128; ++si) {
    const int s = sc * 128 + si;
    const float a = attn[s * 32 + b];
    const float4 v = *(const float4*)(enc + ((size_t)s * 32 + b) * 1024 + ebase);
    acc.x += a * v.x; acc.y += a * v.y; acc.z += a * v.z; acc.w += a * v.w;
  }
  *(float4*)(partial + ((size_t)(sc * 32 + b)) * 1024 + ebase) = acc;
}

// ---------------------------------------------------------------------------
extern "C" void kernel_launch(void* const* d_in, const int* in_sizes, int n_in,
                              void* d_out, int out_size, void* d_ws, size_t ws_size,
                              hipStream_t stream) {
  const float* dec = (const float*)d_in[0];
  const float* enc = (const float*)d_in[1];
  const float* Wb  = (const float*)d_in[2];
  const float* Wc  = (const float*)d_in[3];
  const float* Wa  = (const float*)d_in[4];
  float* out = (float*)d_out;
  (void)in_sizes; (void)n_in; (void)out_size;

  char* ws = (char*)d_ws;
  const size_t ENC_BF = (size_t)MROWS * 1024 * 2;          // 128 MB
  const size_t NEED = ENC_BF + (2u<<20) + (128u<<10) + (256u<<10) + (256u<<10) + (2u<<20);

  if (ws_size >= NEED) {
    unsigned short* encBf = (unsigned short*)ws;
    char* p = ws + ENC_BF;
    unsigned short* WcBf = (unsigned short*)p;               p += (2u<<20);
    float* wsum    = (float*)p;                              p += (128u<<10);
    float* score   = (float*)p;                              p += (256u<<10);
    float* attn    = (float*)p;                              p += (256u<<10);
    float* partial = (float*)p;

    conv_kernel<<<2048, 256, 0, stream>>>(enc, encBf);
    prep_kernel<<<96, 256, 0, stream>>>(dec, Wb, Wc, WcBf, wsum);
    score_kernel<<<1024, 256, 0, stream>>>(encBf, WcBf, wsum, Wa, score);
    softmax_kernel<<<32, 256, 0, stream>>>(score, attn);
    ctx_partial_bf16<<<512, 256, 0, stream>>>(encBf, attn, partial);
    ctx_reduce_kernel<<<32, 256, 0, stream>>>(partial, out);
  } else {
    unsigned short* WcBf = (unsigned short*)ws;
    float* wsum    = (float*)(ws + (2u << 20));
    float* score   = (float*)(ws + (2u << 20) + (128u << 10));
    float* attn    = (float*)(ws + (2u << 20) + (384u << 10));
    float* partial = (float*)(ws + (2u << 20) + (640u << 10));

    prep_kernel<<<96, 256, 0, stream>>>(dec, Wb, Wc, WcBf, wsum);
    score_f32_kernel<<<512, 256, 0, stream>>>(enc, WcBf, wsum, Wa, score);
    softmax_kernel<<<32, 256, 0, stream>>>(score, attn);
    ctx_partial_f32<<<512, 256, 0, stream>>>(enc, attn, partial);
    ctx_reduce_kernel<<<32, 256, 0, stream>>>(partial, out);
  }
}